// Round 10
// baseline (873.102 us; speedup 1.0000x reference)
//
#include <hip/hip_runtime.h>

#define N_NODES 100000
#define N_EDGES 1600000
#define T_STEPS 6
#define FDIM    64
#define SEG     (T_STEPS * N_NODES)
#define C2      0.01f
#define NB      ((SEG + 255) / 256)   // scan blocks = 2344

// ---- CSR build: counts -> exclusive scan -> fill. Built once, used twice. ----

__global__ __launch_bounds__(256) void k_count(
    const int* __restrict__ dst, const int* __restrict__ tix,
    int* __restrict__ cnt_i)
{
  const int e = blockIdx.x * blockDim.x + threadIdx.x;
  if (e >= N_EDGES) return;
  atomicAdd(&cnt_i[tix[e] * N_NODES + dst[e]], 1);
}

// Per-block exclusive scan (Hillis-Steele in LDS) + block totals.
__global__ __launch_bounds__(256) void k_scan1(
    const int* __restrict__ cnt_i, int* __restrict__ offs, int* __restrict__ bsum)
{
  __shared__ int sh[256];
  const int gid = blockIdx.x * 256 + threadIdx.x;
  const int v = (gid < SEG) ? cnt_i[gid] : 0;
  sh[threadIdx.x] = v;
  __syncthreads();
  #pragma unroll
  for (int o = 1; o < 256; o <<= 1) {
    const int add = (threadIdx.x >= o) ? sh[threadIdx.x - o] : 0;
    __syncthreads();
    sh[threadIdx.x] += add;
    __syncthreads();
  }
  if (gid < SEG) offs[gid] = sh[threadIdx.x] - v;   // exclusive
  if (threadIdx.x == 255) bsum[blockIdx.x] = sh[255];
}

// Single-block scan of the 2344 block totals (exclusive, with running carry).
__global__ __launch_bounds__(256) void k_scan2(int* __restrict__ bsum, int nb)
{
  __shared__ int sh[256];
  __shared__ int carry_sh;
  if (threadIdx.x == 0) carry_sh = 0;
  __syncthreads();
  for (int base = 0; base < nb; base += 256) {
    const int i = base + threadIdx.x;
    const int v = (i < nb) ? bsum[i] : 0;
    sh[threadIdx.x] = v;
    __syncthreads();
    #pragma unroll
    for (int o = 1; o < 256; o <<= 1) {
      const int add = (threadIdx.x >= o) ? sh[threadIdx.x - o] : 0;
      __syncthreads();
      sh[threadIdx.x] += add;
      __syncthreads();
    }
    const int carry = carry_sh;
    if (i < nb) bsum[i] = carry + sh[threadIdx.x] - v;
    __syncthreads();
    if (threadIdx.x == 255) carry_sh = carry + sh[255];
    __syncthreads();
  }
}

// Add block offsets; also emit fill cursors and the float cnt array (exact
// small ints -- bit-identical to what k_sum6 used to write each layer).
__global__ __launch_bounds__(256) void k_scan3(
    const int* __restrict__ cnt_i, const int* __restrict__ bsum,
    int* __restrict__ offs, int* __restrict__ curs, float* __restrict__ cntf)
{
  const int gid = blockIdx.x * 256 + threadIdx.x;
  if (gid >= SEG) return;
  const int o = offs[gid] + bsum[blockIdx.x];
  offs[gid] = o;
  curs[gid] = o;
  cntf[gid] = (float)cnt_i[gid];
  if (gid == 0) offs[SEG] = N_EDGES;
}

// Scatter src node ids into CSR slots (arrival order within a segment is an
// arbitrary permutation -- r1 vs r5 proved segment-sum order is benign).
__global__ __launch_bounds__(256) void k_fill(
    const int* __restrict__ src, const int* __restrict__ dst,
    const int* __restrict__ tix, int* __restrict__ curs,
    int* __restrict__ csr_src)
{
  const int e = blockIdx.x * blockDim.x + threadIdx.x;
  if (e >= N_EDGES) return;
  const int slot = atomicAdd(&curs[tix[e] * N_NODES + dst[e]], 1);
  csr_src[slot] = src[e];
}

// One wave per NODE, lane = feature. Walk the node's 6 CSR ranges
// concurrently: per iteration 6 independent index loads + 6 independent
// 256B gathers, NO dependent pointer chain (the k_sum6 latency killer).
__global__ __launch_bounds__(256) void k_sum_csr(
    const float* __restrict__ feat, const int* __restrict__ csr_src,
    const int* __restrict__ offs, float* __restrict__ sums)
{
  const int lane = threadIdx.x & 63;
  const int n = blockIdx.x * (blockDim.x >> 6) + (threadIdx.x >> 6);
  if (n >= N_NODES) return;

  int it0 = offs[0 * N_NODES + n], et0 = offs[0 * N_NODES + n + 1];
  int it1 = offs[1 * N_NODES + n], et1 = offs[1 * N_NODES + n + 1];
  int it2 = offs[2 * N_NODES + n], et2 = offs[2 * N_NODES + n + 1];
  int it3 = offs[3 * N_NODES + n], et3 = offs[3 * N_NODES + n + 1];
  int it4 = offs[4 * N_NODES + n], et4 = offs[4 * N_NODES + n + 1];
  int it5 = offs[5 * N_NODES + n], et5 = offs[5 * N_NODES + n + 1];

  float v0 = 0.f, v1 = 0.f, v2 = 0.f, v3 = 0.f, v4 = 0.f, v5 = 0.f;

  while ((it0 < et0) | (it1 < et1) | (it2 < et2) |
         (it3 < et3) | (it4 < et4) | (it5 < et5)) {
    if (it0 < et0) { v0 += feat[(size_t)csr_src[it0] * FDIM + lane]; ++it0; }
    if (it1 < et1) { v1 += feat[(size_t)csr_src[it1] * FDIM + lane]; ++it1; }
    if (it2 < et2) { v2 += feat[(size_t)csr_src[it2] * FDIM + lane]; ++it2; }
    if (it3 < et3) { v3 += feat[(size_t)csr_src[it3] * FDIM + lane]; ++it3; }
    if (it4 < et4) { v4 += feat[(size_t)csr_src[it4] * FDIM + lane]; ++it4; }
    if (it5 < et5) { v5 += feat[(size_t)csr_src[it5] * FDIM + lane]; ++it5; }
  }

  sums[((size_t)0 * N_NODES + n) * FDIM + lane] = v0;
  sums[((size_t)1 * N_NODES + n) * FDIM + lane] = v1;
  sums[((size_t)2 * N_NODES + n) * FDIM + lane] = v2;
  sums[((size_t)3 * N_NODES + n) * FDIM + lane] = v3;
  sums[((size_t)4 * N_NODES + n) * FDIM + lane] = v4;
  sums[((size_t)5 * N_NODES + n) * FDIM + lane] = v5;
}

// ===== VERBATIM round-9 gemm (passed, absmax 128) -- do not touch. =====
template <int OUTF, int JBLK>
__global__ __launch_bounds__(64) void k_fused_gemm(
    const float* __restrict__ sums, const float* __restrict__ cnt,
    const float* __restrict__ W, const float* __restrict__ bias,
    float* __restrict__ out)
{
  constexpr int JW = OUTF / JBLK;             // 2 j-slices per node group
  const int lane = threadIdx.x;               // 64-thread block = 1 wave
  const int grp  = blockIdx.x / JW;
  const int jb   = (blockIdx.x % JW) * JBLK;  // block-uniform j-slice

  int n = grp * 64 + lane;
  const bool valid = (n < N_NODES);
  if (!valid) n = N_NODES - 1;

  // ---- pass A: scale factors per t (round-1 arithmetic, q fully unrolled) ----
  float sc0, sc1, sc2, sc3, sc4, sc5;
  #pragma unroll
  for (int t = 0; t < T_STEPS; ++t) {
    const float c  = cnt[(size_t)t * N_NODES + n];
    const float rc = 1.0f / fmaxf(c, 1.0f);
    const float4* row = (const float4*)(sums + ((size_t)t * N_NODES + n) * FDIM);
    float ss = 0.0f;
    #pragma unroll
    for (int q = 0; q < FDIM / 4; ++q) {
      float4 v = row[q];
      float m0 = v.x * rc, m1 = v.y * rc, m2 = v.z * rc, m3 = v.w * rc;
      ss += m0 * m0 + m1 * m1 + m2 * m2 + m3 * m3;
    }
    const float norm = 1.0f - C2 * ss;
    const float s = rc / norm;
    if (t == 0) sc0 = s; else if (t == 1) sc1 = s; else if (t == 2) sc2 = s;
    else if (t == 3) sc3 = s; else if (t == 4) sc4 = s; else sc5 = s;
  }

  // ---- pass B: dense layer, j-slice [jb, jb+JBLK), q8 fully unrolled ----
  float acc[JBLK];
  #pragma unroll
  for (int j = 0; j < JBLK; ++j) acc[j] = bias[jb + j];

  #pragma unroll 1
  for (int t = 0; t < T_STEPS; ++t) {
    const float s = (t == 0) ? sc0 : (t == 1) ? sc1 : (t == 2) ? sc2
                  : (t == 3) ? sc3 : (t == 4) ? sc4 : sc5;
    const float4* row = (const float4*)(sums + ((size_t)t * N_NODES + n) * FDIM);
    #pragma unroll
    for (int q8 = 0; q8 < FDIM / 8; ++q8) {
      const float4 a = row[q8 * 2 + 0];
      const float4 b4 = row[q8 * 2 + 1];
      const float hv[8] = {a.x, a.y, a.z, a.w, b4.x, b4.y, b4.z, b4.w};
      const float* wr = W + ((size_t)t * FDIM + q8 * 8) * OUTF + jb;
      #pragma unroll
      for (int i = 0; i < 8; ++i) {
        const float hs = hv[i] * s;
        #pragma unroll
        for (int j = 0; j < JBLK; ++j)
          acc[j] = fmaf(hs, wr[i * OUTF + j], acc[j]);
      }
    }
  }

  if (valid) {
    float* o = out + (size_t)n * OUTF + jb;
    #pragma unroll
    for (int j = 0; j < JBLK; ++j) o[j] = fmaxf(acc[j], 0.0f);
  }
}
// ===== end verbatim round-9 gemm =====

extern "C" void kernel_launch(void* const* d_in, const int* in_sizes, int n_in,
                              void* d_out, int out_size, void* d_ws, size_t ws_size,
                              hipStream_t stream) {
  const float* x  = (const float*)d_in[0];
  const int*  ei  = (const int*)d_in[1];
  const int*  tix = (const int*)d_in[2];
  const float* W1 = (const float*)d_in[3];
  const float* b1 = (const float*)d_in[4];
  const float* W2 = (const float*)d_in[5];
  const float* b2 = (const float*)d_in[6];

  const int* src = ei;
  const int* dst = ei + N_EDGES;

  // Workspace: cnt_i[SEG] | offs[SEG+1] | bsum[2560] | curs[SEG] | csr_src[NE]
  //          | cntf[SEG] | sums[SEG*64] | h1[NN*64]   (~195 MB)
  int*   cnt_i   = (int*)d_ws;
  int*   offs    = cnt_i + SEG;
  int*   bsum    = offs + (SEG + 1);
  int*   curs    = bsum + 2560;               // NB=2344, padded
  int*   csr_src = curs + SEG;
  float* cntf    = (float*)(csr_src + N_EDGES);
  float* sums    = cntf + SEG + 3;            // +3 -> 16B-aligned for float4
  float* h1      = sums + (size_t)SEG * FDIM;

  const int node_grid = (N_NODES + 3) / 4;    // 4 waves/block, wave per node
  const int ngrp = (N_NODES + 63) / 64;
  const int gemm_blocks = ngrp * 2;

  // CSR build (once, reused by both layers)
  hipMemsetAsync(cnt_i, 0, (size_t)SEG * sizeof(int), stream);
  k_count<<<(N_EDGES + 255) / 256, 256, 0, stream>>>(dst, tix, cnt_i);
  k_scan1<<<NB, 256, 0, stream>>>(cnt_i, offs, bsum);
  k_scan2<<<1, 256, 0, stream>>>(bsum, NB);
  k_scan3<<<NB, 256, 0, stream>>>(cnt_i, bsum, offs, curs, cntf);
  k_fill<<<(N_EDGES + 255) / 256, 256, 0, stream>>>(src, dst, tix, curs, csr_src);

  // Layer 1
  k_sum_csr<<<node_grid, 256, 0, stream>>>(x, csr_src, offs, sums);
  k_fused_gemm<64, 32><<<gemm_blocks, 64, 0, stream>>>(sums, cntf, W1, b1, h1);

  // Layer 2 (same CSR, same cntf)
  k_sum_csr<<<node_grid, 256, 0, stream>>>(h1, csr_src, offs, sums);
  k_fused_gemm<16, 8><<<gemm_blocks, 64, 0, stream>>>(sums, cntf, W2, b2, (float*)d_out);
}